// Round 3
// baseline (524.232 us; speedup 1.0000x reference)
//
#include <hip/hip_runtime.h>

// Problem constants
#define BB 16
#define NN 1024
#define FIN 64
#define FOUT 128
#define DD 64
#define HH 4
#define NEG 0.2f

#define RT 32     // rows per block
#define CT 128    // column tile in K2

typedef __attribute__((ext_vector_type(8))) short short8;
typedef __attribute__((ext_vector_type(4))) float f32x4;

__device__ __forceinline__ unsigned short f2bf(float x) {
    union { float f; unsigned u; } v; v.f = x;
    unsigned r = v.u + 0x7fffu + ((v.u >> 16) & 1u);
    return (unsigned short)(r >> 16);
}
__device__ __forceinline__ float bf2f(unsigned short s) {
    union { float f; unsigned u; } v; v.u = ((unsigned)s) << 16;
    return v.f;
}

#define MFMA(a, b, c) __builtin_amdgcn_mfma_f32_16x16x32_bf16((a), (b), (c), 0, 0, 0)

// ---------------- Kernel 1: h_prime (bf16 transposed), attn_src/dst (bf16 hi/lo), hp_sum ----------------
// grid: BB*(NN/RT) blocks, 256 threads
__global__ __launch_bounds__(256) void gat_k1(
    const float* __restrict__ h,      // [B,N,FIN]
    const float* __restrict__ w,      // [H,FIN,FOUT]
    const float* __restrict__ a_src,  // [H,FOUT,DD]
    const float* __restrict__ a_dst,  // [H,FOUT,DD]
    unsigned short* __restrict__ asHg,  // [B,H,N,DD] bf16 hi
    unsigned short* __restrict__ asLg,  // lo
    unsigned short* __restrict__ adHg,
    unsigned short* __restrict__ adLg,
    unsigned short* __restrict__ hpTg,  // [B,H,FOUT,N] bf16 (transposed h')
    float* __restrict__ hpsum)          // [B,N,FOUT]
{
    __shared__ float hL[RT][FIN + 1];      // 32x65
    __shared__ float wL[FIN][FOUT + 2];    // 64x130
    __shared__ float hpL[RT][FOUT + 2];    // 32x130

    const int t  = threadIdx.x;
    const int tx = t & 31;
    const int ty = t >> 5;           // 0..7
    const int blk = blockIdx.x;
    const int b   = blk / (NN / RT);
    const int n0  = (blk % (NN / RT)) * RT;

    // load h tile (RT x FIN)
    for (int idx = t; idx < RT * FIN / 4; idx += 256) {
        int r = (idx * 4) / FIN;
        int f = (idx * 4) % FIN;
        float4 v = *reinterpret_cast<const float4*>(&h[((size_t)b * NN + n0 + r) * FIN + f]);
        hL[r][f + 0] = v.x; hL[r][f + 1] = v.y; hL[r][f + 2] = v.z; hL[r][f + 3] = v.w;
    }

    float sum_acc[4][4];
#pragma unroll
    for (int i = 0; i < 4; i++)
#pragma unroll
        for (int j = 0; j < 4; j++) sum_acc[i][j] = 0.f;

    for (int hh = 0; hh < HH; ++hh) {
        __syncthreads();  // protect wL/hpL from previous iteration readers
        for (int idx = t; idx < FIN * FOUT / 4; idx += 256) {
            int k = (idx * 4) / FOUT;
            int o = (idx * 4) % FOUT;
            float4 v = *reinterpret_cast<const float4*>(&w[((size_t)hh * FIN + k) * FOUT + o]);
            wL[k][o + 0] = v.x; wL[k][o + 1] = v.y; wL[k][o + 2] = v.z; wL[k][o + 3] = v.w;
        }
        __syncthreads();

        float acc[4][4];
#pragma unroll
        for (int i = 0; i < 4; i++)
#pragma unroll
            for (int j = 0; j < 4; j++) acc[i][j] = 0.f;

#pragma unroll 8
        for (int k = 0; k < FIN; k++) {
            float av0 = hL[ty][k], av1 = hL[ty + 8][k], av2 = hL[ty + 16][k], av3 = hL[ty + 24][k];
            float bv0 = wL[k][tx], bv1 = wL[k][tx + 32], bv2 = wL[k][tx + 64], bv3 = wL[k][tx + 96];
            acc[0][0] += av0 * bv0; acc[0][1] += av0 * bv1; acc[0][2] += av0 * bv2; acc[0][3] += av0 * bv3;
            acc[1][0] += av1 * bv0; acc[1][1] += av1 * bv1; acc[1][2] += av1 * bv2; acc[1][3] += av1 * bv3;
            acc[2][0] += av2 * bv0; acc[2][1] += av2 * bv1; acc[2][2] += av2 * bv2; acc[2][3] += av2 * bv3;
            acc[3][0] += av3 * bv0; acc[3][1] += av3 * bv1; acc[3][2] += av3 * bv2; acc[3][3] += av3 * bv3;
        }

        const size_t bh = (size_t)b * HH + hh;
#pragma unroll
        for (int i = 0; i < 4; i++) {
            int r = i * 8 + ty;
#pragma unroll
            for (int j = 0; j < 4; j++) {
                int o = j * 32 + tx;
                hpL[r][o] = acc[i][j];
                sum_acc[i][j] += acc[i][j];
            }
        }
        __syncthreads();

        // attn_src / attn_dst
        float as0[4], as1[4], ad0[4], ad1[4];
#pragma unroll
        for (int i = 0; i < 4; i++) { as0[i] = 0.f; as1[i] = 0.f; ad0[i] = 0.f; ad1[i] = 0.f; }

#pragma unroll 4
        for (int o = 0; o < FOUT; o++) {
            size_t aoff = ((size_t)hh * FOUT + o) * DD;
            float sv0 = a_src[aoff + tx];
            float sv1 = a_src[aoff + tx + 32];
            float dv0 = a_dst[aoff + tx];
            float dv1 = a_dst[aoff + tx + 32];
#pragma unroll
            for (int i = 0; i < 4; i++) {
                float hv = hpL[i * 8 + ty][o];
                as0[i] += hv * sv0; as1[i] += hv * sv1;
                ad0[i] += hv * dv0; ad1[i] += hv * dv1;
            }
        }
#pragma unroll
        for (int i = 0; i < 4; i++) {
            int r = i * 8 + ty;
            size_t base = (bh * NN + n0 + r) * DD;
            unsigned short h0, h1;
            h0 = f2bf(as0[i]); asHg[base + tx]      = h0; asLg[base + tx]      = f2bf(as0[i] - bf2f(h0));
            h1 = f2bf(as1[i]); asHg[base + tx + 32] = h1; asLg[base + tx + 32] = f2bf(as1[i] - bf2f(h1));
            h0 = f2bf(ad0[i]); adHg[base + tx]      = h0; adLg[base + tx]      = f2bf(ad0[i] - bf2f(h0));
            h1 = f2bf(ad1[i]); adHg[base + tx + 32] = h1; adLg[base + tx + 32] = f2bf(ad1[i] - bf2f(h1));
        }

        // transposed bf16 h' : hpT[bh][o][n]
        {
            int o = t & 127, half = t >> 7;
            size_t dst = (bh * FOUT + o) * NN + n0 + half * 16;
            short8 v0, v1;
#pragma unroll
            for (int k = 0; k < 8; k++) v0[k] = (short)f2bf(hpL[half * 16 + k][o]);
#pragma unroll
            for (int k = 0; k < 8; k++) v1[k] = (short)f2bf(hpL[half * 16 + 8 + k][o]);
            *reinterpret_cast<short8*>(&hpTg[dst])     = v0;
            *reinterpret_cast<short8*>(&hpTg[dst + 8]) = v1;
        }
    }

    // hp_sum (over heads)
#pragma unroll
    for (int i = 0; i < 4; i++) {
        int r = i * 8 + ty;
        size_t rowoff = ((size_t)b * NN + n0 + r) * FOUT;
#pragma unroll
        for (int j = 0; j < 4; j++) {
            hpsum[rowoff + j * 32 + tx] = sum_acc[i][j];
        }
    }
}

// stage one CT x DD hi/lo bf16 tile into swizzled LDS via global_load_lds width=16.
// LDS dest is linear per chunk; the swizzle is applied by permuting the GLOBAL
// source column (m173 pattern).
__device__ __forceinline__ void stage_tile(
    const unsigned short* gH, const unsigned short* gL,
    unsigned short* sH, unsigned short* sL, int w, int l)
{
#pragma unroll
    for (int i = 0; i < 4; i++) {
        int c = i * 256 + w * 64 + l;           // chunk index 0..1023
        int r = c >> 3;                          // row 0..127
        int j = (c & 7) ^ (r & 7);               // inverse-swizzled source chunk
        const unsigned short* srcH = gH + r * DD + j * 8;
        const unsigned short* srcL = gL + r * DD + j * 8;
        unsigned short* dH = sH + (size_t)(i * 256 + w * 64) * 8;  // wave-uniform base
        unsigned short* dL = sL + (size_t)(i * 256 + w * 64) * 8;
        __builtin_amdgcn_global_load_lds(
            (const __attribute__((address_space(1))) unsigned int*)srcH,
            (__attribute__((address_space(3))) unsigned int*)dH, 16, 0, 0);
        __builtin_amdgcn_global_load_lds(
            (const __attribute__((address_space(1))) unsigned int*)srcL,
            (__attribute__((address_space(3))) unsigned int*)dL, 16, 0, 0);
    }
}

// split-bf16 score tile: sacc[rf][cf] += asH*adH + asH*adL + asL*adH
__device__ __forceinline__ void score_tile(
    const unsigned short* adHs, const unsigned short* adLs,
    const short8 aH[2][2], const short8 aL[2][2],
    int w, int li, int g, f32x4 sacc[2][2])
{
#pragma unroll
    for (int ks = 0; ks < 2; ks++) {
        short8 bH[2], bL[2];
#pragma unroll
        for (int cf = 0; cf < 2; cf++) {
            int c = w * 32 + cf * 16 + li;
            int off = c * 64 + ((ks * 32 + g * 8) ^ ((c & 7) * 8));
            bH[cf] = *reinterpret_cast<const short8*>(&adHs[off]);
            bL[cf] = *reinterpret_cast<const short8*>(&adLs[off]);
        }
        __builtin_amdgcn_s_setprio(1);
#pragma unroll
        for (int rf = 0; rf < 2; rf++)
#pragma unroll
            for (int cf = 0; cf < 2; cf++) {
                sacc[rf][cf] = MFMA(aH[rf][ks], bH[cf], sacc[rf][cf]);
                sacc[rf][cf] = MFMA(aH[rf][ks], bL[cf], sacc[rf][cf]);
                sacc[rf][cf] = MFMA(aL[rf][ks], bH[cf], sacc[rf][cf]);
            }
        __builtin_amdgcn_s_setprio(0);
    }
}

// ---------------- Kernel 2: MFMA scores -> softmax -> attn + PV + epilogue ----------------
// grid: BB*(NN/RT) blocks, 256 threads (4 waves). LDS = 40 KB -> 4 blocks/CU.
__global__ __launch_bounds__(256, 4) void gat_k2(
    const float* __restrict__ mask,   // [B,1,N,N]
    const float* __restrict__ bias,   // [FOUT]
    const unsigned short* __restrict__ asHg,
    const unsigned short* __restrict__ asLg,
    const unsigned short* __restrict__ adHg,
    const unsigned short* __restrict__ adLg,
    const unsigned short* __restrict__ hpTg,  // [B,H,FOUT,N]
    const float* __restrict__ hpsum,  // [B,N,FOUT]
    float* __restrict__ out,          // [B,N,FOUT]
    float* __restrict__ attn)         // [B,H,N,N]
{
    __shared__ __align__(16) unsigned short adHs[CT * 64];    // 16 KB
    __shared__ __align__(16) unsigned short adLs[CT * 64];    // 16 KB
    __shared__ __align__(16) unsigned short pBs[RT * 128];    // 8 KB (aliases: red)

    float2* red  = reinterpret_cast<float2*>(pBs);            // [4][32]
    float*  outL = reinterpret_cast<float*>(adHs);            // 32x128 f32 (epilogue)

    const int t  = threadIdx.x;
    const int l  = t & 63;
    const int w  = t >> 6;
    const int li = l & 15;
    const int g  = l >> 4;

    // XCD-aware bijective swizzle: consecutive logical row-tiles on one XCD
    const int lb = (blockIdx.x & 7) * 64 + (blockIdx.x >> 3);
    const int b  = lb >> 5;
    const int n0 = (lb & 31) * RT;

    f32x4 oacc[2][2];
#pragma unroll
    for (int rf = 0; rf < 2; rf++)
#pragma unroll
        for (int of = 0; of < 2; of++) oacc[rf][of] = f32x4{0.f, 0.f, 0.f, 0.f};

    for (int hh = 0; hh < HH; hh++) {
        const size_t bh = (size_t)b * HH + hh;

        // A fragments straight from global (rows rf*16+li, k = ks*32+g*8)
        short8 aH[2][2], aL[2][2];
#pragma unroll
        for (int rf = 0; rf < 2; rf++)
#pragma unroll
            for (int ks = 0; ks < 2; ks++) {
                size_t src = (bh * NN + n0 + rf * 16 + li) * DD + ks * 32 + g * 8;
                aH[rf][ks] = *reinterpret_cast<const short8*>(&asHg[src]);
                aL[rf][ks] = *reinterpret_cast<const short8*>(&asLg[src]);
            }

        float mreg[2][4], lreg[2][4];
#pragma unroll
        for (int rf = 0; rf < 2; rf++)
#pragma unroll
            for (int q = 0; q < 4; q++) { mreg[rf][q] = -3.0e38f; lreg[rf][q] = 0.f; }

        // ================= pass 1: online (m,l) =================
        for (int ct = 0; ct < NN / CT; ct++) {
            __syncthreads();  // B0: protect adHs/adLs reuse
            stage_tile(adHg + (bh * NN + (size_t)ct * CT) * DD,
                       adLg + (bh * NN + (size_t)ct * CT) * DD, adHs, adLs, w, l);
            __syncthreads();  // B1 (compiler drains vmcnt)

            f32x4 sacc[2][2];
#pragma unroll
            for (int rf = 0; rf < 2; rf++)
#pragma unroll
                for (int cf = 0; cf < 2; cf++) sacc[rf][cf] = f32x4{0.f, 0.f, 0.f, 0.f};
            score_tile(adHs, adLs, aH, aL, w, li, g, sacc);

#pragma unroll
            for (int rf = 0; rf < 2; rf++)
#pragma unroll
                for (int q = 0; q < 4; q++) {
                    float v0 = sacc[rf][0][q]; v0 = v0 > 0.f ? v0 : NEG * v0;
                    float v1 = sacc[rf][1][q]; v1 = v1 > 0.f ? v1 : NEG * v1;
                    float nm = fmaxf(mreg[rf][q], fmaxf(v0, v1));
                    lreg[rf][q] = lreg[rf][q] * __expf(mreg[rf][q] - nm)
                                + __expf(v0 - nm) + __expf(v1 - nm);
                    mreg[rf][q] = nm;
                }
        }

        // butterfly within 16-lane groups (cols), then cross-wave via LDS
#pragma unroll
        for (int rf = 0; rf < 2; rf++)
#pragma unroll
            for (int q = 0; q < 4; q++) {
                float m = mreg[rf][q], lv = lreg[rf][q];
#pragma unroll
                for (int msk = 1; msk < 16; msk <<= 1) {
                    float om = __shfl_xor(m, msk);
                    float ol = __shfl_xor(lv, msk);
                    float nm = fmaxf(m, om);
                    lv = lv * __expf(m - nm) + ol * __expf(om - nm);
                    m = nm;
                }
                mreg[rf][q] = m; lreg[rf][q] = lv;
            }
        __syncthreads();  // red region (pBs) free
        if (li == 0) {
#pragma unroll
            for (int rf = 0; rf < 2; rf++)
#pragma unroll
                for (int q = 0; q < 4; q++)
                    red[w * 32 + rf * 16 + g * 4 + q] = make_float2(mreg[rf][q], lreg[rf][q]);
        }
        __syncthreads();
        float mf[2][4], linv[2][4];
#pragma unroll
        for (int rf = 0; rf < 2; rf++)
#pragma unroll
            for (int q = 0; q < 4; q++) {
                int row = rf * 16 + g * 4 + q;
                float2 r0 = red[row], r1 = red[32 + row], r2 = red[64 + row], r3 = red[96 + row];
                float m = fmaxf(fmaxf(r0.x, r1.x), fmaxf(r2.x, r3.x));
                float lv = r0.y * __expf(r0.x - m) + r1.y * __expf(r1.x - m)
                         + r2.y * __expf(r2.x - m) + r3.y * __expf(r3.x - m);
                mf[rf][q] = m;
                linv[rf][q] = 1.0f / lv;
            }

        // ================= pass 2: attn + PV =================
        for (int ct = 0; ct < NN / CT; ct++) {
            __syncthreads();  // B0: protect adHs/adLs + pBs reuse (PV of prev tile done)
            stage_tile(adHg + (bh * NN + (size_t)ct * CT) * DD,
                       adLg + (bh * NN + (size_t)ct * CT) * DD, adHs, adLs, w, l);
            __syncthreads();  // B1

            f32x4 sacc[2][2];
#pragma unroll
            for (int rf = 0; rf < 2; rf++)
#pragma unroll
                for (int cf = 0; cf < 2; cf++) sacc[rf][cf] = f32x4{0.f, 0.f, 0.f, 0.f};
            score_tile(adHs, adLs, aH, aL, w, li, g, sacc);

            // normalized p -> pBs (bf16, swizzled)
#pragma unroll
            for (int rf = 0; rf < 2; rf++)
#pragma unroll
                for (int cf = 0; cf < 2; cf++)
#pragma unroll
                    for (int q = 0; q < 4; q++) {
                        float v = sacc[rf][cf][q];
                        v = v > 0.f ? v : NEG * v;
                        float p = __expf(v - mf[rf][q]) * linv[rf][q];
                        int row = rf * 16 + g * 4 + q;
                        int c = w * 32 + cf * 16 + li;
                        pBs[row * 128 + (c ^ ((row & 15) * 8))] = f2bf(p);
                    }
            __syncthreads();  // B2: pBs ready

            // cooperative: attn = p*mask (coalesced), write masked p back to pBs
            {
                int row = t >> 3, cb = (t & 7) * 16;
                int o0 = row * 128 + ((cb)     ^ ((row & 15) * 8));
                int o1 = row * 128 + ((cb + 8) ^ ((row & 15) * 8));
                short8 p0 = *reinterpret_cast<short8*>(&pBs[o0]);
                short8 p1 = *reinterpret_cast<short8*>(&pBs[o1]);
                const float* mp = mask + ((size_t)b * NN + n0 + row) * NN + (size_t)ct * CT + cb;
                float* ap = attn + (bh * NN + n0 + row) * NN + (size_t)ct * CT + cb;
                float pv[16];
#pragma unroll
                for (int k = 0; k < 8; k++) pv[k]     = bf2f((unsigned short)p0[k]);
#pragma unroll
                for (int k = 0; k < 8; k++) pv[k + 8] = bf2f((unsigned short)p1[k]);
#pragma unroll
                for (int k4 = 0; k4 < 4; k4++) {
                    float4 mv = *reinterpret_cast<const float4*>(&mp[k4 * 4]);
                    float4 av;
                    av.x = pv[k4 * 4 + 0] * mv.x; av.y = pv[k4 * 4 + 1] * mv.y;
                    av.z = pv[k4 * 4 + 2] * mv.z; av.w = pv[k4 * 4 + 3] * mv.w;
                    *reinterpret_cast<float4*>(&ap[k4 * 4]) = av;
                    pv[k4 * 4 + 0] = av.x; pv[k4 * 4 + 1] = av.y;
                    pv[k4 * 4 + 2] = av.z; pv[k4 * 4 + 3] = av.w;
                }
                short8 q0, q1;
#pragma unroll
                for (int k = 0; k < 8; k++) { q0[k] = (short)f2bf(pv[k]); q1[k] = (short)f2bf(pv[k + 8]); }
                *reinterpret_cast<short8*>(&pBs[o0]) = q0;
                *reinterpret_cast<short8*>(&pBs[o1]) = q1;
            }
            __syncthreads();  // B3: masked pBs ready

            // PV: out[r][o] += P[r][c] * hpT[o][c]; B-fragments straight from global (L2)
            const unsigned short* hpb = hpTg + (bh * FOUT) * NN + (size_t)ct * CT;
#pragma unroll
            for (int kc = 0; kc < 4; kc++) {
                short8 pa[2], hb[2];
#pragma unroll
                for (int rf = 0; rf < 2; rf++) {
                    int r = rf * 16 + li;
                    int k = kc * 32 + g * 8;
                    pa[rf] = *reinterpret_cast<const short8*>(&pBs[r * 128 + (k ^ ((r & 15) * 8))]);
                }
#pragma unroll
                for (int of = 0; of < 2; of++) {
                    int o = w * 32 + of * 16 + li;
                    hb[of] = *reinterpret_cast<const short8*>(&hpb[(size_t)o * NN + kc * 32 + g * 8]);
                }
                __builtin_amdgcn_s_setprio(1);
#pragma unroll
                for (int rf = 0; rf < 2; rf++)
#pragma unroll
                    for (int of = 0; of < 2; of++)
                        oacc[rf][of] = MFMA(pa[rf], hb[of], oacc[rf][of]);
                __builtin_amdgcn_s_setprio(0);
            }
        }
    }

    // epilogue: stage oacc -> LDS (reuse adHs as f32 32x128), then coalesced out write
    __syncthreads();
#pragma unroll
    for (int rf = 0; rf < 2; rf++)
#pragma unroll
        for (int of = 0; of < 2; of++)
#pragma unroll
            for (int q = 0; q < 4; q++) {
                int row = rf * 16 + g * 4 + q;
                int col = w * 32 + of * 16 + li;
                outL[row * 128 + col] = oacc[rf][of][q];
            }
    __syncthreads();
    {
        int row = t >> 3, cb = (t & 7) * 16;
        size_t obase = ((size_t)b * NN + n0 + row) * FOUT + cb;
#pragma unroll
        for (int k4 = 0; k4 < 4; k4++) {
            float4 v  = *reinterpret_cast<float4*>(&outL[row * 128 + cb + k4 * 4]);
            float4 bs = *reinterpret_cast<const float4*>(&bias[cb + k4 * 4]);
            float4 hs = *reinterpret_cast<const float4*>(&hpsum[obase + k4 * 4]);
            v.x += bs.x + hs.x; v.y += bs.y + hs.y; v.z += bs.z + hs.z; v.w += bs.w + hs.w;
            *reinterpret_cast<float4*>(&out[obase + k4 * 4]) = v;
        }
    }
}

extern "C" void kernel_launch(void* const* d_in, const int* in_sizes, int n_in,
                              void* d_out, int out_size, void* d_ws, size_t ws_size,
                              hipStream_t stream) {
    const float* h      = (const float*)d_in[0];
    const float* mask   = (const float*)d_in[1];
    const float* w      = (const float*)d_in[2];
    const float* a_src  = (const float*)d_in[3];
    const float* a_dst  = (const float*)d_in[4];
    const float* bias   = (const float*)d_in[5];

    float* out  = (float*)d_out;                          // [B,N,FOUT]
    float* attn = out + (size_t)BB * NN * FOUT;           // [B,H,N,N]

    // workspace layout (56 MB total)
    const size_t NASD = (size_t)BB * HH * NN * DD;        // 4M elems
    unsigned short* asHg = (unsigned short*)d_ws;
    unsigned short* asLg = asHg + NASD;
    unsigned short* adHg = asLg + NASD;
    unsigned short* adLg = adHg + NASD;
    unsigned short* hpTg = adLg + NASD;                   // B*H*FOUT*N = 8M elems
    float* hpsum = (float*)(hpTg + (size_t)BB * HH * FOUT * NN);

    dim3 grid(BB * (NN / RT));
    dim3 block(256);
    gat_k1<<<grid, block, 0, stream>>>(h, w, a_src, a_dst, asHg, asLg, adHg, adLg, hpTg, hpsum);
    gat_k2<<<grid, block, 0, stream>>>(mask, bias, asHg, asLg, adHg, adLg, hpTg, hpsum, out, attn);
}

// Round 4
// 446.701 us; speedup vs baseline: 1.1736x; 1.1736x over previous
//
#include <hip/hip_runtime.h>

// Problem constants
#define BB 16
#define NN 1024
#define FIN 64
#define FOUT 128
#define DD 64
#define HH 4
#define NEG 0.2f

#define RT 32     // rows per block in K1
#define RT2 16    // rows per block in K2
#define CT 128    // column tile in K2

typedef __attribute__((ext_vector_type(8))) short short8;
typedef __attribute__((ext_vector_type(4))) float f32x4;

__device__ __forceinline__ unsigned short f2bf(float x) {
    union { float f; unsigned u; } v; v.f = x;
    unsigned r = v.u + 0x7fffu + ((v.u >> 16) & 1u);
    return (unsigned short)(r >> 16);
}
__device__ __forceinline__ float bf2f(unsigned short s) {
    union { float f; unsigned u; } v; v.u = ((unsigned)s) << 16;
    return v.f;
}

#define MFMA(a, b, c) __builtin_amdgcn_mfma_f32_16x16x32_bf16((a), (b), (c), 0, 0, 0)

// ---------------- Kernel 1: h_prime (bf16 fragment-packed), attn_src/dst (bf16 hi/lo), hp_sum ----------------
// grid: BB*(NN/RT) blocks, 256 threads
__global__ __launch_bounds__(256) void gat_k1(
    const float* __restrict__ h,      // [B,N,FIN]
    const float* __restrict__ w,      // [H,FIN,FOUT]
    const float* __restrict__ a_src,  // [H,FOUT,DD]
    const float* __restrict__ a_dst,  // [H,FOUT,DD]
    unsigned short* __restrict__ asHg,  // [B,H,N,DD] bf16 hi
    unsigned short* __restrict__ asLg,  // lo
    unsigned short* __restrict__ adHg,
    unsigned short* __restrict__ adLg,
    unsigned short* __restrict__ hpPg,  // [B*H][N/32][FOUT][32] bf16 fragment-packed h'
    float* __restrict__ hpsum)          // [B,N,FOUT]
{
    __shared__ float hL[RT][FIN + 1];      // 32x65
    __shared__ float wL[FIN][FOUT + 2];    // 64x130
    __shared__ float hpL[RT][FOUT + 2];    // 32x130

    const int t  = threadIdx.x;
    const int tx = t & 31;
    const int ty = t >> 5;           // 0..7
    const int blk = blockIdx.x;
    const int b   = blk / (NN / RT);
    const int n0  = (blk % (NN / RT)) * RT;

    // load h tile (RT x FIN)
    for (int idx = t; idx < RT * FIN / 4; idx += 256) {
        int r = (idx * 4) / FIN;
        int f = (idx * 4) % FIN;
        float4 v = *reinterpret_cast<const float4*>(&h[((size_t)b * NN + n0 + r) * FIN + f]);
        hL[r][f + 0] = v.x; hL[r][f + 1] = v.y; hL[r][f + 2] = v.z; hL[r][f + 3] = v.w;
    }

    float sum_acc[4][4];
#pragma unroll
    for (int i = 0; i < 4; i++)
#pragma unroll
        for (int j = 0; j < 4; j++) sum_acc[i][j] = 0.f;

    for (int hh = 0; hh < HH; ++hh) {
        __syncthreads();  // protect wL/hpL from previous iteration readers
        for (int idx = t; idx < FIN * FOUT / 4; idx += 256) {
            int k = (idx * 4) / FOUT;
            int o = (idx * 4) % FOUT;
            float4 v = *reinterpret_cast<const float4*>(&w[((size_t)hh * FIN + k) * FOUT + o]);
            wL[k][o + 0] = v.x; wL[k][o + 1] = v.y; wL[k][o + 2] = v.z; wL[k][o + 3] = v.w;
        }
        __syncthreads();

        float acc[4][4];
#pragma unroll
        for (int i = 0; i < 4; i++)
#pragma unroll
            for (int j = 0; j < 4; j++) acc[i][j] = 0.f;

#pragma unroll 8
        for (int k = 0; k < FIN; k++) {
            float av0 = hL[ty][k], av1 = hL[ty + 8][k], av2 = hL[ty + 16][k], av3 = hL[ty + 24][k];
            float bv0 = wL[k][tx], bv1 = wL[k][tx + 32], bv2 = wL[k][tx + 64], bv3 = wL[k][tx + 96];
            acc[0][0] += av0 * bv0; acc[0][1] += av0 * bv1; acc[0][2] += av0 * bv2; acc[0][3] += av0 * bv3;
            acc[1][0] += av1 * bv0; acc[1][1] += av1 * bv1; acc[1][2] += av1 * bv2; acc[1][3] += av1 * bv3;
            acc[2][0] += av2 * bv0; acc[2][1] += av2 * bv1; acc[2][2] += av2 * bv2; acc[2][3] += av2 * bv3;
            acc[3][0] += av3 * bv0; acc[3][1] += av3 * bv1; acc[3][2] += av3 * bv2; acc[3][3] += av3 * bv3;
        }

        const size_t bh = (size_t)b * HH + hh;
#pragma unroll
        for (int i = 0; i < 4; i++) {
            int r = i * 8 + ty;
#pragma unroll
            for (int j = 0; j < 4; j++) {
                int o = j * 32 + tx;
                hpL[r][o] = acc[i][j];
                sum_acc[i][j] += acc[i][j];
            }
        }
        __syncthreads();

        // attn_src / attn_dst
        float as0[4], as1[4], ad0[4], ad1[4];
#pragma unroll
        for (int i = 0; i < 4; i++) { as0[i] = 0.f; as1[i] = 0.f; ad0[i] = 0.f; ad1[i] = 0.f; }

#pragma unroll 4
        for (int o = 0; o < FOUT; o++) {
            size_t aoff = ((size_t)hh * FOUT + o) * DD;
            float sv0 = a_src[aoff + tx];
            float sv1 = a_src[aoff + tx + 32];
            float dv0 = a_dst[aoff + tx];
            float dv1 = a_dst[aoff + tx + 32];
#pragma unroll
            for (int i = 0; i < 4; i++) {
                float hv = hpL[i * 8 + ty][o];
                as0[i] += hv * sv0; as1[i] += hv * sv1;
                ad0[i] += hv * dv0; ad1[i] += hv * dv1;
            }
        }
#pragma unroll
        for (int i = 0; i < 4; i++) {
            int r = i * 8 + ty;
            size_t base = (bh * NN + n0 + r) * DD;
            unsigned short h0, h1;
            h0 = f2bf(as0[i]); asHg[base + tx]      = h0; asLg[base + tx]      = f2bf(as0[i] - bf2f(h0));
            h1 = f2bf(as1[i]); asHg[base + tx + 32] = h1; asLg[base + tx + 32] = f2bf(as1[i] - bf2f(h1));
            h0 = f2bf(ad0[i]); adHg[base + tx]      = h0; adLg[base + tx]      = f2bf(ad0[i] - bf2f(h0));
            h1 = f2bf(ad1[i]); adHg[base + tx + 32] = h1; adLg[base + tx + 32] = f2bf(ad1[i] - bf2f(h1));
        }

        // fragment-packed bf16 h' : hpP[bh][n0/32][o][r]  (r = n - n0)
        {
            int o = t & 127, half = t >> 7;
            size_t dst = ((bh * (NN / 32) + (n0 >> 5)) * FOUT + o) * 32 + half * 16;
            short8 v0, v1;
#pragma unroll
            for (int k = 0; k < 8; k++) v0[k] = (short)f2bf(hpL[half * 16 + k][o]);
#pragma unroll
            for (int k = 0; k < 8; k++) v1[k] = (short)f2bf(hpL[half * 16 + 8 + k][o]);
            *reinterpret_cast<short8*>(&hpPg[dst])     = v0;
            *reinterpret_cast<short8*>(&hpPg[dst + 8]) = v1;
        }
    }

    // hp_sum (over heads)
#pragma unroll
    for (int i = 0; i < 4; i++) {
        int r = i * 8 + ty;
        size_t rowoff = ((size_t)b * NN + n0 + r) * FOUT;
#pragma unroll
        for (int j = 0; j < 4; j++) {
            hpsum[rowoff + j * 32 + tx] = sum_acc[i][j];
        }
    }
}

// ---------------- Kernel 2: MFMA scores -> softmax -> attn + PV + epilogue ----------------
// grid: BB*(NN/RT2) = 1024 blocks, 256 threads (4 waves). LDS = 8 KB.
__global__ __launch_bounds__(256, 4) void gat_k2(
    const float* __restrict__ mask,   // [B,1,N,N]
    const float* __restrict__ bias,   // [FOUT]
    const unsigned short* __restrict__ asHg,
    const unsigned short* __restrict__ asLg,
    const unsigned short* __restrict__ adHg,
    const unsigned short* __restrict__ adLg,
    const unsigned short* __restrict__ hpPg,  // [B*H][N/32][FOUT][32]
    const float* __restrict__ hpsum,  // [B,N,FOUT]
    float* __restrict__ out,          // [B,N,FOUT]
    float* __restrict__ attn)         // [B,H,N,N]
{
    __shared__ __align__(16) unsigned char smem[RT2 * FOUT * 4];  // 8 KB
    unsigned short* pBs = reinterpret_cast<unsigned short*>(smem);      // 16x128 bf16 (4 KB)
    float2* red = reinterpret_cast<float2*>(smem + RT2 * FOUT * 2);     // [4][16] (512 B)
    float* outL = reinterpret_cast<float*>(smem);                       // 16x128 f32 (epilogue)

    const int t  = threadIdx.x;
    const int l  = t & 63;
    const int w  = t >> 6;
    const int li = l & 15;
    const int g  = l >> 4;

    // XCD-aware bijective swizzle (1024 % 8 == 0)
    const int lb = (blockIdx.x & 7) * 128 + (blockIdx.x >> 3);
    const int b  = lb >> 6;
    const int n0 = (lb & 63) * RT2;

    f32x4 oacc[2];
    oacc[0] = f32x4{0.f, 0.f, 0.f, 0.f};
    oacc[1] = f32x4{0.f, 0.f, 0.f, 0.f};

    for (int hh = 0; hh < HH; hh++) {
        const size_t bh = (size_t)b * HH + hh;

        // A fragments straight from global (row n0+li, k = ks*32+g*8)
        short8 aH[2], aL[2];
#pragma unroll
        for (int ks = 0; ks < 2; ks++) {
            size_t src = (bh * NN + n0 + li) * DD + ks * 32 + g * 8;
            aH[ks] = *reinterpret_cast<const short8*>(&asHg[src]);
            aL[ks] = *reinterpret_cast<const short8*>(&asLg[src]);
        }

        const unsigned short* adHb = adHg + bh * NN * DD;
        const unsigned short* adLb = adLg + bh * NN * DD;

        float mreg[4], lreg[4];
#pragma unroll
        for (int q = 0; q < 4; q++) { mreg[q] = -3.0e38f; lreg[q] = 0.f; }

        // ================= pass 1: online (m,l) — ZERO barriers =================
        for (int ct = 0; ct < NN / CT; ct++) {
            short8 bH[2][2], bL[2][2];
#pragma unroll
            for (int cf = 0; cf < 2; cf++)
#pragma unroll
                for (int ks = 0; ks < 2; ks++) {
                    size_t off = (size_t)(ct * CT + w * 32 + cf * 16 + li) * DD + ks * 32 + g * 8;
                    bH[cf][ks] = *reinterpret_cast<const short8*>(&adHb[off]);
                    bL[cf][ks] = *reinterpret_cast<const short8*>(&adLb[off]);
                }
            f32x4 sacc[2];
            sacc[0] = f32x4{0.f, 0.f, 0.f, 0.f};
            sacc[1] = f32x4{0.f, 0.f, 0.f, 0.f};
            __builtin_amdgcn_s_setprio(1);
#pragma unroll
            for (int ks = 0; ks < 2; ks++)
#pragma unroll
                for (int cf = 0; cf < 2; cf++) {
                    sacc[cf] = MFMA(aH[ks], bH[cf][ks], sacc[cf]);
                    sacc[cf] = MFMA(aH[ks], bL[cf][ks], sacc[cf]);
                    sacc[cf] = MFMA(aL[ks], bH[cf][ks], sacc[cf]);
                }
            __builtin_amdgcn_s_setprio(0);
#pragma unroll
            for (int q = 0; q < 4; q++) {
                float v0 = sacc[0][q]; v0 = v0 > 0.f ? v0 : NEG * v0;
                float v1 = sacc[1][q]; v1 = v1 > 0.f ? v1 : NEG * v1;
                float nm = fmaxf(mreg[q], fmaxf(v0, v1));
                lreg[q] = lreg[q] * __expf(mreg[q] - nm)
                        + __expf(v0 - nm) + __expf(v1 - nm);
                mreg[q] = nm;
            }
        }

        // butterfly within 16-lane groups, then cross-wave via LDS
#pragma unroll
        for (int q = 0; q < 4; q++) {
            float m = mreg[q], lv = lreg[q];
#pragma unroll
            for (int msk = 1; msk < 16; msk <<= 1) {
                float om = __shfl_xor(m, msk);
                float ol = __shfl_xor(lv, msk);
                float nm = fmaxf(m, om);
                lv = lv * __expf(m - nm) + ol * __expf(om - nm);
                m = nm;
            }
            mreg[q] = m; lreg[q] = lv;
        }
        __syncthreads();  // all waves done pass 1; red region free
        if (li == 0) {
#pragma unroll
            for (int q = 0; q < 4; q++)
                red[w * 16 + g * 4 + q] = make_float2(mreg[q], lreg[q]);
        }
        __syncthreads();
        float mf[4], linv[4];
#pragma unroll
        for (int q = 0; q < 4; q++) {
            int row = g * 4 + q;
            float2 r0 = red[row], r1 = red[16 + row], r2 = red[32 + row], r3 = red[48 + row];
            float m = fmaxf(fmaxf(r0.x, r1.x), fmaxf(r2.x, r3.x));
            float lv = r0.y * __expf(r0.x - m) + r1.y * __expf(r1.x - m)
                     + r2.y * __expf(r2.x - m) + r3.y * __expf(r3.x - m);
            mf[q] = m;
            linv[q] = 1.0f / lv;
        }

        // ================= pass 2: attn + PV =================
        for (int ct = 0; ct < NN / CT; ct++) {
            short8 bH[2][2], bL[2][2];
#pragma unroll
            for (int cf = 0; cf < 2; cf++)
#pragma unroll
                for (int ks = 0; ks < 2; ks++) {
                    size_t off = (size_t)(ct * CT + w * 32 + cf * 16 + li) * DD + ks * 32 + g * 8;
                    bH[cf][ks] = *reinterpret_cast<const short8*>(&adHb[off]);
                    bL[cf][ks] = *reinterpret_cast<const short8*>(&adLb[off]);
                }
            f32x4 sacc[2];
            sacc[0] = f32x4{0.f, 0.f, 0.f, 0.f};
            sacc[1] = f32x4{0.f, 0.f, 0.f, 0.f};
            __builtin_amdgcn_s_setprio(1);
#pragma unroll
            for (int ks = 0; ks < 2; ks++)
#pragma unroll
                for (int cf = 0; cf < 2; cf++) {
                    sacc[cf] = MFMA(aH[ks], bH[cf][ks], sacc[cf]);
                    sacc[cf] = MFMA(aH[ks], bL[cf][ks], sacc[cf]);
                    sacc[cf] = MFMA(aL[ks], bH[cf][ks], sacc[cf]);
                }
            __builtin_amdgcn_s_setprio(0);

            // p, mask (register layout, 64B sectors), attn store; keep masked p
            float pm[2][4];
#pragma unroll
            for (int cf = 0; cf < 2; cf++)
#pragma unroll
                for (int q = 0; q < 4; q++) {
                    float v = sacc[cf][q];
                    v = v > 0.f ? v : NEG * v;
                    float p = __expf(v - mf[q]) * linv[q];
                    int row = g * 4 + q;
                    int c = ct * CT + w * 32 + cf * 16 + li;
                    float mv = mask[((size_t)b * NN + n0 + row) * NN + c];
                    float pmv = p * mv;
                    attn[(bh * NN + n0 + row) * NN + c] = pmv;
                    pm[cf][q] = pmv;
                }
            __syncthreads();  // B0: previous PV reads of pBs complete
#pragma unroll
            for (int cf = 0; cf < 2; cf++)
#pragma unroll
                for (int q = 0; q < 4; q++) {
                    int row = g * 4 + q;
                    int c = w * 32 + cf * 16 + li;
                    pBs[row * 128 + (c ^ (row * 8))] = f2bf(pm[cf][q]);
                }
            __syncthreads();  // B1: pBs ready

            // PV: A = P rows (LDS transpose), B = hpP packed (contiguous 1KB/wave loads)
            const unsigned short* hpb = hpPg + (bh * (NN / 32) + (size_t)ct * 4) * FOUT * 32;
#pragma unroll
            for (int kc = 0; kc < 4; kc++) {
                int k = kc * 32 + g * 8;
                short8 pa = *reinterpret_cast<const short8*>(&pBs[li * 128 + (k ^ (li * 8))]);
                short8 hb0 = *reinterpret_cast<const short8*>(
                    &hpb[((size_t)kc * FOUT + w * 32 + li) * 32 + g * 8]);
                short8 hb1 = *reinterpret_cast<const short8*>(
                    &hpb[((size_t)kc * FOUT + w * 32 + 16 + li) * 32 + g * 8]);
                __builtin_amdgcn_s_setprio(1);
                oacc[0] = MFMA(pa, hb0, oacc[0]);
                oacc[1] = MFMA(pa, hb1, oacc[1]);
                __builtin_amdgcn_s_setprio(0);
            }
        }
    }

    // epilogue: stage oacc -> LDS (f32 16x128), then coalesced out write
    __syncthreads();
#pragma unroll
    for (int of = 0; of < 2; of++)
#pragma unroll
        for (int q = 0; q < 4; q++) {
            int row = g * 4 + q;
            int col = w * 32 + of * 16 + li;
            outL[row * 128 + col] = oacc[of][q];
        }
    __syncthreads();
    {
        int row = t >> 4, cb = (t & 15) * 8;
        size_t obase = ((size_t)b * NN + n0 + row) * FOUT + cb;
#pragma unroll
        for (int k4 = 0; k4 < 2; k4++) {
            float4 v  = *reinterpret_cast<float4*>(&outL[row * 128 + cb + k4 * 4]);
            float4 bs = *reinterpret_cast<const float4*>(&bias[cb + k4 * 4]);
            float4 hs = *reinterpret_cast<const float4*>(&hpsum[obase + k4 * 4]);
            v.x += bs.x + hs.x; v.y += bs.y + hs.y; v.z += bs.z + hs.z; v.w += bs.w + hs.w;
            *reinterpret_cast<float4*>(&out[obase + k4 * 4]) = v;
        }
    }
}

extern "C" void kernel_launch(void* const* d_in, const int* in_sizes, int n_in,
                              void* d_out, int out_size, void* d_ws, size_t ws_size,
                              hipStream_t stream) {
    const float* h      = (const float*)d_in[0];
    const float* mask   = (const float*)d_in[1];
    const float* w      = (const float*)d_in[2];
    const float* a_src  = (const float*)d_in[3];
    const float* a_dst  = (const float*)d_in[4];
    const float* bias   = (const float*)d_in[5];

    float* out  = (float*)d_out;                          // [B,N,FOUT]
    float* attn = out + (size_t)BB * NN * FOUT;           // [B,H,N,N]

    // workspace layout (56 MB total)
    const size_t NASD = (size_t)BB * HH * NN * DD;        // 4M elems
    unsigned short* asHg = (unsigned short*)d_ws;
    unsigned short* asLg = asHg + NASD;
    unsigned short* adHg = asLg + NASD;
    unsigned short* adLg = adHg + NASD;
    unsigned short* hpPg = adLg + NASD;                   // B*H*FOUT*N = 8M elems
    float* hpsum = (float*)(hpPg + (size_t)BB * HH * FOUT * NN);

    dim3 block(256);
    gat_k1<<<dim3(BB * (NN / RT)),  block, 0, stream>>>(h, w, a_src, a_dst, asHg, asLg, adHg, adLg, hpPg, hpsum);
    gat_k2<<<dim3(BB * (NN / RT2)), block, 0, stream>>>(mask, bias, asHg, asLg, adHg, adLg, hpPg, hpsum, out, attn);
}

// Round 5
// 407.316 us; speedup vs baseline: 1.2870x; 1.0967x over previous
//
#include <hip/hip_runtime.h>

// Problem constants
#define BB 16
#define NN 1024
#define FIN 64
#define FOUT 128
#define DD 64
#define HH 4
#define NEG 0.2f

#define RT 32     // rows per block in K1
#define RT2 16    // rows per block in K2
#define CT 128    // column tile in K2

typedef __attribute__((ext_vector_type(8))) short short8;
typedef __attribute__((ext_vector_type(4))) float f32x4;

__device__ __forceinline__ unsigned short f2bf(float x) {
    union { float f; unsigned u; } v; v.f = x;
    unsigned r = v.u + 0x7fffu + ((v.u >> 16) & 1u);
    return (unsigned short)(r >> 16);
}
__device__ __forceinline__ float bf2f(unsigned short s) {
    union { float f; unsigned u; } v; v.u = ((unsigned)s) << 16;
    return v.f;
}

#define MFMA(a, b, c) __builtin_amdgcn_mfma_f32_16x16x32_bf16((a), (b), (c), 0, 0, 0)

// ---------------- Kernel 1: h_prime (bf16 fragment-packed), attn_src/dst (bf16 hi/lo), hp_sum ----------------
// grid: BB*(NN/RT) blocks, 256 threads
__global__ __launch_bounds__(256) void gat_k1(
    const float* __restrict__ h,      // [B,N,FIN]
    const float* __restrict__ w,      // [H,FIN,FOUT]
    const float* __restrict__ a_src,  // [H,FOUT,DD]
    const float* __restrict__ a_dst,  // [H,FOUT,DD]
    unsigned short* __restrict__ asHg,  // [B,H,N,DD] bf16 hi
    unsigned short* __restrict__ asLg,  // lo
    unsigned short* __restrict__ adHg,
    unsigned short* __restrict__ adLg,
    unsigned short* __restrict__ hpPg,  // [B*H][N/32][FOUT][32] bf16 fragment-packed h'
    float* __restrict__ hpsum)          // [B,N,FOUT]
{
    __shared__ float hL[RT][FIN + 1];      // 32x65
    __shared__ float wL[FIN][FOUT + 2];    // 64x130
    __shared__ float hpL[RT][FOUT + 2];    // 32x130

    const int t  = threadIdx.x;
    const int tx = t & 31;
    const int ty = t >> 5;           // 0..7
    const int blk = blockIdx.x;
    const int b   = blk / (NN / RT);
    const int n0  = (blk % (NN / RT)) * RT;

    // load h tile (RT x FIN)
    for (int idx = t; idx < RT * FIN / 4; idx += 256) {
        int r = (idx * 4) / FIN;
        int f = (idx * 4) % FIN;
        float4 v = *reinterpret_cast<const float4*>(&h[((size_t)b * NN + n0 + r) * FIN + f]);
        hL[r][f + 0] = v.x; hL[r][f + 1] = v.y; hL[r][f + 2] = v.z; hL[r][f + 3] = v.w;
    }

    float sum_acc[4][4];
#pragma unroll
    for (int i = 0; i < 4; i++)
#pragma unroll
        for (int j = 0; j < 4; j++) sum_acc[i][j] = 0.f;

    for (int hh = 0; hh < HH; ++hh) {
        __syncthreads();  // protect wL/hpL from previous iteration readers
        for (int idx = t; idx < FIN * FOUT / 4; idx += 256) {
            int k = (idx * 4) / FOUT;
            int o = (idx * 4) % FOUT;
            float4 v = *reinterpret_cast<const float4*>(&w[((size_t)hh * FIN + k) * FOUT + o]);
            wL[k][o + 0] = v.x; wL[k][o + 1] = v.y; wL[k][o + 2] = v.z; wL[k][o + 3] = v.w;
        }
        __syncthreads();

        float acc[4][4];
#pragma unroll
        for (int i = 0; i < 4; i++)
#pragma unroll
            for (int j = 0; j < 4; j++) acc[i][j] = 0.f;

#pragma unroll 8
        for (int k = 0; k < FIN; k++) {
            float av0 = hL[ty][k], av1 = hL[ty + 8][k], av2 = hL[ty + 16][k], av3 = hL[ty + 24][k];
            float bv0 = wL[k][tx], bv1 = wL[k][tx + 32], bv2 = wL[k][tx + 64], bv3 = wL[k][tx + 96];
            acc[0][0] += av0 * bv0; acc[0][1] += av0 * bv1; acc[0][2] += av0 * bv2; acc[0][3] += av0 * bv3;
            acc[1][0] += av1 * bv0; acc[1][1] += av1 * bv1; acc[1][2] += av1 * bv2; acc[1][3] += av1 * bv3;
            acc[2][0] += av2 * bv0; acc[2][1] += av2 * bv1; acc[2][2] += av2 * bv2; acc[2][3] += av2 * bv3;
            acc[3][0] += av3 * bv0; acc[3][1] += av3 * bv1; acc[3][2] += av3 * bv2; acc[3][3] += av3 * bv3;
        }

        const size_t bh = (size_t)b * HH + hh;
#pragma unroll
        for (int i = 0; i < 4; i++) {
            int r = i * 8 + ty;
#pragma unroll
            for (int j = 0; j < 4; j++) {
                int o = j * 32 + tx;
                hpL[r][o] = acc[i][j];
                sum_acc[i][j] += acc[i][j];
            }
        }
        __syncthreads();

        // attn_src / attn_dst
        float as0[4], as1[4], ad0[4], ad1[4];
#pragma unroll
        for (int i = 0; i < 4; i++) { as0[i] = 0.f; as1[i] = 0.f; ad0[i] = 0.f; ad1[i] = 0.f; }

#pragma unroll 4
        for (int o = 0; o < FOUT; o++) {
            size_t aoff = ((size_t)hh * FOUT + o) * DD;
            float sv0 = a_src[aoff + tx];
            float sv1 = a_src[aoff + tx + 32];
            float dv0 = a_dst[aoff + tx];
            float dv1 = a_dst[aoff + tx + 32];
#pragma unroll
            for (int i = 0; i < 4; i++) {
                float hv = hpL[i * 8 + ty][o];
                as0[i] += hv * sv0; as1[i] += hv * sv1;
                ad0[i] += hv * dv0; ad1[i] += hv * dv1;
            }
        }
#pragma unroll
        for (int i = 0; i < 4; i++) {
            int r = i * 8 + ty;
            size_t base = (bh * NN + n0 + r) * DD;
            unsigned short h0, h1;
            h0 = f2bf(as0[i]); asHg[base + tx]      = h0; asLg[base + tx]      = f2bf(as0[i] - bf2f(h0));
            h1 = f2bf(as1[i]); asHg[base + tx + 32] = h1; asLg[base + tx + 32] = f2bf(as1[i] - bf2f(h1));
            h0 = f2bf(ad0[i]); adHg[base + tx]      = h0; adLg[base + tx]      = f2bf(ad0[i] - bf2f(h0));
            h1 = f2bf(ad1[i]); adHg[base + tx + 32] = h1; adLg[base + tx + 32] = f2bf(ad1[i] - bf2f(h1));
        }

        // fragment-packed bf16 h' : hpP[bh][n0/32][o][r]  (r = n - n0)
        {
            int o = t & 127, half = t >> 7;
            size_t dst = ((bh * (NN / 32) + (n0 >> 5)) * FOUT + o) * 32 + half * 16;
            short8 v0, v1;
#pragma unroll
            for (int k = 0; k < 8; k++) v0[k] = (short)f2bf(hpL[half * 16 + k][o]);
#pragma unroll
            for (int k = 0; k < 8; k++) v1[k] = (short)f2bf(hpL[half * 16 + 8 + k][o]);
            *reinterpret_cast<short8*>(&hpPg[dst])     = v0;
            *reinterpret_cast<short8*>(&hpPg[dst + 8]) = v1;
        }
    }

    // hp_sum (over heads)
#pragma unroll
    for (int i = 0; i < 4; i++) {
        int r = i * 8 + ty;
        size_t rowoff = ((size_t)b * NN + n0 + r) * FOUT;
#pragma unroll
        for (int j = 0; j < 4; j++) {
            hpsum[rowoff + j * 32 + tx] = sum_acc[i][j];
        }
    }
}

#define MLDS (NN + 8)   // padded maskL row stride

// pass B: p from score cache -> attn (NT store) -> pBs transpose -> PV
template <bool FIRST>
__device__ __forceinline__ void pass_b(
    int b, int n0, int w, int li, int g, size_t bh,
    const float (&sc)[8][2][4], const float (&mf)[4], const float (&linv)[4],
    const float* __restrict__ mask, float* __restrict__ attn,
    const unsigned short* __restrict__ hpPg,
    unsigned short* pBs0, unsigned short* pBs1, unsigned short* maskL,
    f32x4 (&oacc)[2])
{
    const unsigned short* hpbase = hpPg + bh * (NN / 32) * FOUT * 32;
    float mcur[8];
    if (FIRST) {
#pragma unroll
        for (int cf = 0; cf < 2; cf++)
#pragma unroll
            for (int q = 0; q < 4; q++)
                mcur[cf * 4 + q] = __builtin_nontemporal_load(
                    &mask[((size_t)b * NN + n0 + g * 4 + q) * NN + w * 32 + cf * 16 + li]);
    }
#pragma unroll
    for (int ct = 0; ct < 8; ct++) {
        float mnext[8];
        if (FIRST && ct < 7) {
#pragma unroll
            for (int cf = 0; cf < 2; cf++)
#pragma unroll
                for (int q = 0; q < 4; q++)
                    mnext[cf * 4 + q] = __builtin_nontemporal_load(
                        &mask[((size_t)b * NN + n0 + g * 4 + q) * NN + (ct + 1) * CT + w * 32 + cf * 16 + li]);
        }
        unsigned short* pB = (ct & 1) ? pBs1 : pBs0;
        float pm[2][4];
#pragma unroll
        for (int cf = 0; cf < 2; cf++)
#pragma unroll
            for (int q = 0; q < 4; q++) {
                int row = g * 4 + q;
                int cl  = w * 32 + cf * 16 + li;
                int cg  = ct * CT + cl;
                float p = __expf(sc[ct][cf][q] - mf[q]) * linv[q];
                float mv;
                if (FIRST) {
                    mv = mcur[cf * 4 + q];
                    maskL[row * MLDS + cg] = f2bf(mv);
                } else {
                    mv = bf2f(maskL[row * MLDS + cg]);
                }
                float pmv = p * mv;
                __builtin_nontemporal_store(pmv, &attn[(bh * NN + n0 + row) * NN + cg]);
                pm[cf][q] = pmv;
            }
#pragma unroll
        for (int cf = 0; cf < 2; cf++)
#pragma unroll
            for (int q = 0; q < 4; q++) {
                int row = g * 4 + q;
                int cl  = w * 32 + cf * 16 + li;
                pB[row * 128 + (cl ^ (row * 8))] = f2bf(pm[cf][q]);
            }
        __syncthreads();  // pB ready (double-buffered: only 1 barrier per tile)

        const unsigned short* hpb = hpbase + (size_t)ct * 4 * FOUT * 32;
#pragma unroll
        for (int kc = 0; kc < 4; kc++) {
            int k = kc * 32 + g * 8;
            short8 pa  = *reinterpret_cast<const short8*>(&pB[li * 128 + (k ^ (li * 8))]);
            short8 hb0 = *reinterpret_cast<const short8*>(
                &hpb[((size_t)kc * FOUT + w * 32 + li) * 32 + g * 8]);
            short8 hb1 = *reinterpret_cast<const short8*>(
                &hpb[((size_t)kc * FOUT + w * 32 + 16 + li) * 32 + g * 8]);
            __builtin_amdgcn_s_setprio(1);
            oacc[0] = MFMA(pa, hb0, oacc[0]);
            oacc[1] = MFMA(pa, hb1, oacc[1]);
            __builtin_amdgcn_s_setprio(0);
        }
        if (FIRST) {
#pragma unroll
            for (int i = 0; i < 8; i++) mcur[i] = mnext[i];
        }
    }
}

// ---------------- Kernel 2: MFMA scores (reg-cached) -> softmax -> attn + PV + epilogue ----------------
// grid: BB*(NN/RT2) = 1024 blocks, 256 threads (4 waves). LDS ~41.7 KB -> 3 blocks/CU.
__global__ __launch_bounds__(256, 3) void gat_k2(
    const float* __restrict__ mask,   // [B,1,N,N]
    const float* __restrict__ bias,   // [FOUT]
    const unsigned short* __restrict__ asHg,
    const unsigned short* __restrict__ asLg,
    const unsigned short* __restrict__ adHg,
    const unsigned short* __restrict__ adLg,
    const unsigned short* __restrict__ hpPg,  // [B*H][N/32][FOUT][32]
    const float* __restrict__ hpsum,  // [B,N,FOUT]
    float* __restrict__ out,          // [B,N,FOUT]
    float* __restrict__ attn)         // [B,H,N,N]
{
    __shared__ __align__(16) unsigned char smem[8192 + RT2 * MLDS * 2 + 512];
    unsigned short* pBs0  = reinterpret_cast<unsigned short*>(smem);            // 4 KB
    unsigned short* pBs1  = reinterpret_cast<unsigned short*>(smem + 4096);     // 4 KB
    float*          outL  = reinterpret_cast<float*>(smem);                     // 8 KB (epilogue)
    unsigned short* maskL = reinterpret_cast<unsigned short*>(smem + 8192);     // 33 KB
    float2*         red   = reinterpret_cast<float2*>(smem + 8192 + RT2 * MLDS * 2);

    const int t  = threadIdx.x;
    const int l  = t & 63;
    const int w  = t >> 6;
    const int li = l & 15;
    const int g  = l >> 4;

    // XCD-aware bijective swizzle (1024 % 8 == 0)
    const int lb = (blockIdx.x & 7) * 128 + (blockIdx.x >> 3);
    const int b  = lb >> 6;
    const int n0 = (lb & 63) * RT2;

    f32x4 oacc[2];
    oacc[0] = f32x4{0.f, 0.f, 0.f, 0.f};
    oacc[1] = f32x4{0.f, 0.f, 0.f, 0.f};

    for (int hh = 0; hh < HH; hh++) {
        const size_t bh = (size_t)b * HH + hh;

        // A fragments (read-once per block -> NT loads)
        short8 aH[2], aL[2];
#pragma unroll
        for (int ks = 0; ks < 2; ks++) {
            size_t src = (bh * NN + n0 + li) * DD + ks * 32 + g * 8;
            aH[ks] = __builtin_nontemporal_load(reinterpret_cast<const short8*>(&asHg[src]));
            aL[ks] = __builtin_nontemporal_load(reinterpret_cast<const short8*>(&asLg[src]));
        }

        const unsigned short* adHb = adHg + bh * NN * DD;
        const unsigned short* adLb = adLg + bh * NN * DD;

        // ================= pass A: scores -> register cache (lrelu'd) =================
        float sc[8][2][4];
#pragma unroll
        for (int ct = 0; ct < 8; ct++) {
#pragma unroll
            for (int cf = 0; cf < 2; cf++) {
                short8 bHr[2], bLr[2];
#pragma unroll
                for (int ks = 0; ks < 2; ks++) {
                    size_t off = (size_t)(ct * CT + w * 32 + cf * 16 + li) * DD + ks * 32 + g * 8;
                    bHr[ks] = *reinterpret_cast<const short8*>(&adHb[off]);
                    bLr[ks] = *reinterpret_cast<const short8*>(&adLb[off]);
                }
                f32x4 s = f32x4{0.f, 0.f, 0.f, 0.f};
                __builtin_amdgcn_s_setprio(1);
#pragma unroll
                for (int ks = 0; ks < 2; ks++) {
                    s = MFMA(aH[ks], bHr[ks], s);
                    s = MFMA(aH[ks], bLr[ks], s);
                    s = MFMA(aL[ks], bHr[ks], s);
                }
                __builtin_amdgcn_s_setprio(0);
#pragma unroll
                for (int q = 0; q < 4; q++) {
                    float v = s[q];
                    sc[ct][cf][q] = v > 0.f ? v : NEG * v;
                }
            }
        }

        // ================= softmax stats from cache =================
        float mreg[4], lreg[4];
#pragma unroll
        for (int q = 0; q < 4; q++) {
            float m = -3.0e38f;
#pragma unroll
            for (int ct = 0; ct < 8; ct++)
                m = fmaxf(m, fmaxf(sc[ct][0][q], sc[ct][1][q]));
            float lv = 0.f;
#pragma unroll
            for (int ct = 0; ct < 8; ct++)
                lv += __expf(sc[ct][0][q] - m) + __expf(sc[ct][1][q] - m);
            mreg[q] = m; lreg[q] = lv;
        }
        // butterfly over the 16 li lanes (cols), then cross-wave via LDS
#pragma unroll
        for (int q = 0; q < 4; q++) {
            float m = mreg[q], lv = lreg[q];
#pragma unroll
            for (int msk = 1; msk < 16; msk <<= 1) {
                float om = __shfl_xor(m, msk);
                float ol = __shfl_xor(lv, msk);
                float nm = fmaxf(m, om);
                lv = lv * __expf(m - nm) + ol * __expf(om - nm);
                m = nm;
            }
            mreg[q] = m; lreg[q] = lv;
        }
        __syncthreads();  // red free (prev head's readers done)
        if (li == 0) {
#pragma unroll
            for (int q = 0; q < 4; q++)
                red[w * 16 + g * 4 + q] = make_float2(mreg[q], lreg[q]);
        }
        __syncthreads();
        float mf[4], linv[4];
#pragma unroll
        for (int q = 0; q < 4; q++) {
            int row = g * 4 + q;
            float2 r0 = red[row], r1 = red[16 + row], r2 = red[32 + row], r3 = red[48 + row];
            float m = fmaxf(fmaxf(r0.x, r1.x), fmaxf(r2.x, r3.x));
            float lv = r0.y * __expf(r0.x - m) + r1.y * __expf(r1.x - m)
                     + r2.y * __expf(r2.x - m) + r3.y * __expf(r3.x - m);
            mf[q] = m;
            linv[q] = 1.0f / lv;
        }

        // ================= pass B =================
        if (hh == 0)
            pass_b<true >(b, n0, w, li, g, bh, sc, mf, linv, mask, attn, hpPg, pBs0, pBs1, maskL, oacc);
        else
            pass_b<false>(b, n0, w, li, g, bh, sc, mf, linv, mask, attn, hpPg, pBs0, pBs1, maskL, oacc);
    }

    // epilogue: stage oacc -> LDS (f32 16x128), then coalesced out write
    __syncthreads();
#pragma unroll
    for (int of = 0; of < 2; of++)
#pragma unroll
        for (int q = 0; q < 4; q++) {
            int row = g * 4 + q;
            int col = w * 32 + of * 16 + li;
            outL[row * 128 + col] = oacc[of][q];
        }
    __syncthreads();
    {
        int row = t >> 4, cb = (t & 15) * 8;
        size_t obase = ((size_t)b * NN + n0 + row) * FOUT + cb;
#pragma unroll
        for (int k4 = 0; k4 < 2; k4++) {
            float4 v  = *reinterpret_cast<float4*>(&outL[row * 128 + cb + k4 * 4]);
            float4 bs = *reinterpret_cast<const float4*>(&bias[cb + k4 * 4]);
            float4 hs = *reinterpret_cast<const float4*>(&hpsum[obase + k4 * 4]);
            v.x += bs.x + hs.x; v.y += bs.y + hs.y; v.z += bs.z + hs.z; v.w += bs.w + hs.w;
            *reinterpret_cast<float4*>(&out[obase + k4 * 4]) = v;
        }
    }
}

extern "C" void kernel_launch(void* const* d_in, const int* in_sizes, int n_in,
                              void* d_out, int out_size, void* d_ws, size_t ws_size,
                              hipStream_t stream) {
    const float* h      = (const float*)d_in[0];
    const float* mask   = (const float*)d_in[1];
    const float* w      = (const float*)d_in[2];
    const float* a_src  = (const float*)d_in[3];
    const float* a_dst  = (const float*)d_in[4];
    const float* bias   = (const float*)d_in[5];

    float* out  = (float*)d_out;                          // [B,N,FOUT]
    float* attn = out + (size_t)BB * NN * FOUT;           // [B,H,N,N]

    // workspace layout (56 MB total)
    const size_t NASD = (size_t)BB * HH * NN * DD;        // 4M elems
    unsigned short* asHg = (unsigned short*)d_ws;
    unsigned short* asLg = asHg + NASD;
    unsigned short* adHg = asLg + NASD;
    unsigned short* adLg = adHg + NASD;
    unsigned short* hpPg = adLg + NASD;                   // B*H*FOUT*N = 8M elems
    float* hpsum = (float*)(hpPg + (size_t)BB * HH * FOUT * NN);

    dim3 block(256);
    gat_k1<<<dim3(BB * (NN / RT)),  block, 0, stream>>>(h, w, a_src, a_dst, asHg, asLg, adHg, adLg, hpPg, hpsum);
    gat_k2<<<dim3(BB * (NN / RT2)), block, 0, stream>>>(mask, bias, asHg, asLg, adHg, adLg, hpPg, hpsum, out, attn);
}

// Round 6
// 347.992 us; speedup vs baseline: 1.5064x; 1.1705x over previous
//
#include <hip/hip_runtime.h>

// Problem constants
#define BB 16
#define NN 1024
#define FIN 64
#define FOUT 128
#define DD 64
#define HH 4
#define NEG 0.2f

#define RT 32     // rows per block in K1
#define RT2 16    // rows per block in K2
#define CT 128    // column tile in K2

typedef __attribute__((ext_vector_type(8))) short short8;
typedef __attribute__((ext_vector_type(4))) float f32x4;

__device__ __forceinline__ unsigned short f2bf(float x) {
    union { float f; unsigned u; } v; v.f = x;
    unsigned r = v.u + 0x7fffu + ((v.u >> 16) & 1u);
    return (unsigned short)(r >> 16);
}
__device__ __forceinline__ float bf2f(unsigned short s) {
    union { float f; unsigned u; } v; v.u = ((unsigned)s) << 16;
    return v.f;
}

#define MFMA(a, b, c) __builtin_amdgcn_mfma_f32_16x16x32_bf16((a), (b), (c), 0, 0, 0)

// ---------------- Kernel 1: h_prime (bf16 fragment-packed), attn_src/dst (bf16 hi/lo), hp_sum ----------------
// grid: BB*(NN/RT) blocks, 256 threads
__global__ __launch_bounds__(256) void gat_k1(
    const float* __restrict__ h,      // [B,N,FIN]
    const float* __restrict__ w,      // [H,FIN,FOUT]
    const float* __restrict__ a_src,  // [H,FOUT,DD]
    const float* __restrict__ a_dst,  // [H,FOUT,DD]
    unsigned short* __restrict__ asHg,  // [B,H,N,DD] bf16 hi
    unsigned short* __restrict__ asLg,  // lo
    unsigned short* __restrict__ adHg,
    unsigned short* __restrict__ adLg,
    unsigned short* __restrict__ hpPg,  // [B*H][N/32][FOUT][32] bf16 fragment-packed h'
    float* __restrict__ hpsum)          // [B,N,FOUT]
{
    __shared__ float hL[RT][FIN + 1];      // 32x65
    __shared__ float wL[FIN][FOUT + 2];    // 64x130
    __shared__ float hpL[RT][FOUT + 2];    // 32x130

    const int t  = threadIdx.x;
    const int tx = t & 31;
    const int ty = t >> 5;           // 0..7
    const int blk = blockIdx.x;
    const int b   = blk / (NN / RT);
    const int n0  = (blk % (NN / RT)) * RT;

    // load h tile (RT x FIN)
    for (int idx = t; idx < RT * FIN / 4; idx += 256) {
        int r = (idx * 4) / FIN;
        int f = (idx * 4) % FIN;
        float4 v = *reinterpret_cast<const float4*>(&h[((size_t)b * NN + n0 + r) * FIN + f]);
        hL[r][f + 0] = v.x; hL[r][f + 1] = v.y; hL[r][f + 2] = v.z; hL[r][f + 3] = v.w;
    }

    float sum_acc[4][4];
#pragma unroll
    for (int i = 0; i < 4; i++)
#pragma unroll
        for (int j = 0; j < 4; j++) sum_acc[i][j] = 0.f;

    for (int hh = 0; hh < HH; ++hh) {
        __syncthreads();  // protect wL/hpL from previous iteration readers
        for (int idx = t; idx < FIN * FOUT / 4; idx += 256) {
            int k = (idx * 4) / FOUT;
            int o = (idx * 4) % FOUT;
            float4 v = *reinterpret_cast<const float4*>(&w[((size_t)hh * FIN + k) * FOUT + o]);
            wL[k][o + 0] = v.x; wL[k][o + 1] = v.y; wL[k][o + 2] = v.z; wL[k][o + 3] = v.w;
        }
        __syncthreads();

        float acc[4][4];
#pragma unroll
        for (int i = 0; i < 4; i++)
#pragma unroll
            for (int j = 0; j < 4; j++) acc[i][j] = 0.f;

#pragma unroll 8
        for (int k = 0; k < FIN; k++) {
            float av0 = hL[ty][k], av1 = hL[ty + 8][k], av2 = hL[ty + 16][k], av3 = hL[ty + 24][k];
            float bv0 = wL[k][tx], bv1 = wL[k][tx + 32], bv2 = wL[k][tx + 64], bv3 = wL[k][tx + 96];
            acc[0][0] += av0 * bv0; acc[0][1] += av0 * bv1; acc[0][2] += av0 * bv2; acc[0][3] += av0 * bv3;
            acc[1][0] += av1 * bv0; acc[1][1] += av1 * bv1; acc[1][2] += av1 * bv2; acc[1][3] += av1 * bv3;
            acc[2][0] += av2 * bv0; acc[2][1] += av2 * bv1; acc[2][2] += av2 * bv2; acc[2][3] += av2 * bv3;
            acc[3][0] += av3 * bv0; acc[3][1] += av3 * bv1; acc[3][2] += av3 * bv2; acc[3][3] += av3 * bv3;
        }

        const size_t bh = (size_t)b * HH + hh;
#pragma unroll
        for (int i = 0; i < 4; i++) {
            int r = i * 8 + ty;
#pragma unroll
            for (int j = 0; j < 4; j++) {
                int o = j * 32 + tx;
                hpL[r][o] = acc[i][j];
                sum_acc[i][j] += acc[i][j];
            }
        }
        __syncthreads();

        // attn_src / attn_dst
        float as0[4], as1[4], ad0[4], ad1[4];
#pragma unroll
        for (int i = 0; i < 4; i++) { as0[i] = 0.f; as1[i] = 0.f; ad0[i] = 0.f; ad1[i] = 0.f; }

#pragma unroll 4
        for (int o = 0; o < FOUT; o++) {
            size_t aoff = ((size_t)hh * FOUT + o) * DD;
            float sv0 = a_src[aoff + tx];
            float sv1 = a_src[aoff + tx + 32];
            float dv0 = a_dst[aoff + tx];
            float dv1 = a_dst[aoff + tx + 32];
#pragma unroll
            for (int i = 0; i < 4; i++) {
                float hv = hpL[i * 8 + ty][o];
                as0[i] += hv * sv0; as1[i] += hv * sv1;
                ad0[i] += hv * dv0; ad1[i] += hv * dv1;
            }
        }
#pragma unroll
        for (int i = 0; i < 4; i++) {
            int r = i * 8 + ty;
            size_t base = (bh * NN + n0 + r) * DD;
            unsigned short h0, h1;
            h0 = f2bf(as0[i]); asHg[base + tx]      = h0; asLg[base + tx]      = f2bf(as0[i] - bf2f(h0));
            h1 = f2bf(as1[i]); asHg[base + tx + 32] = h1; asLg[base + tx + 32] = f2bf(as1[i] - bf2f(h1));
            h0 = f2bf(ad0[i]); adHg[base + tx]      = h0; adLg[base + tx]      = f2bf(ad0[i] - bf2f(h0));
            h1 = f2bf(ad1[i]); adHg[base + tx + 32] = h1; adLg[base + tx + 32] = f2bf(ad1[i] - bf2f(h1));
        }

        // fragment-packed bf16 h' : hpP[bh][n0/32][o][r]  (r = n - n0)
        {
            int o = t & 127, half = t >> 7;
            size_t dst = ((bh * (NN / 32) + (n0 >> 5)) * FOUT + o) * 32 + half * 16;
            short8 v0, v1;
#pragma unroll
            for (int k = 0; k < 8; k++) v0[k] = (short)f2bf(hpL[half * 16 + k][o]);
#pragma unroll
            for (int k = 0; k < 8; k++) v1[k] = (short)f2bf(hpL[half * 16 + 8 + k][o]);
            *reinterpret_cast<short8*>(&hpPg[dst])     = v0;
            *reinterpret_cast<short8*>(&hpPg[dst + 8]) = v1;
        }
    }

    // hp_sum (over heads)
#pragma unroll
    for (int i = 0; i < 4; i++) {
        int r = i * 8 + ty;
        size_t rowoff = ((size_t)b * NN + n0 + r) * FOUT;
#pragma unroll
        for (int j = 0; j < 4; j++) {
            hpsum[rowoff + j * 32 + tx] = sum_acc[i][j];
        }
    }
}

#define MLDS (NN + 8)   // padded maskL row stride

// pass B: p from score cache -> attn -> pBs transpose -> PV (hb loads issued pre-barrier)
template <bool FIRST>
__device__ __forceinline__ void pass_b(
    int b, int n0, int w, int li, int g, size_t bh,
    const float (&sc)[8][2][4], const float (&mf)[4], const float (&linv)[4],
    const float* __restrict__ mask, float* __restrict__ attn,
    const unsigned short* __restrict__ hpPg,
    unsigned short* pBs0, unsigned short* pBs1, unsigned short* maskL,
    f32x4 (&oacc)[2])
{
    const unsigned short* hpbase = hpPg + bh * (NN / 32) * FOUT * 32;
    float mcur[8];
    if (FIRST) {
#pragma unroll
        for (int cf = 0; cf < 2; cf++)
#pragma unroll
            for (int q = 0; q < 4; q++)
                mcur[cf * 4 + q] = __builtin_nontemporal_load(
                    &mask[((size_t)b * NN + n0 + g * 4 + q) * NN + w * 32 + cf * 16 + li]);
    }
#pragma unroll
    for (int ct = 0; ct < 8; ct++) {
        float mnext[8];
        if (FIRST && ct < 7) {
#pragma unroll
            for (int cf = 0; cf < 2; cf++)
#pragma unroll
                for (int q = 0; q < 4; q++)
                    mnext[cf * 4 + q] = __builtin_nontemporal_load(
                        &mask[((size_t)b * NN + n0 + g * 4 + q) * NN + (ct + 1) * CT + w * 32 + cf * 16 + li]);
        }
        unsigned short* pB = (ct & 1) ? pBs1 : pBs0;
        float pm[2][4];
#pragma unroll
        for (int cf = 0; cf < 2; cf++)
#pragma unroll
            for (int q = 0; q < 4; q++) {
                int row = g * 4 + q;
                int cl  = w * 32 + cf * 16 + li;
                int cg  = ct * CT + cl;
                float p = __expf(sc[ct][cf][q] - mf[q]) * linv[q];
                float mv;
                if (FIRST) {
                    mv = mcur[cf * 4 + q];
                    maskL[row * MLDS + cg] = f2bf(mv);
                } else {
                    mv = bf2f(maskL[row * MLDS + cg]);
                }
                float pmv = p * mv;
                attn[(bh * NN + n0 + row) * NN + cg] = pmv;
                pm[cf][q] = pmv;
            }
#pragma unroll
        for (int cf = 0; cf < 2; cf++)
#pragma unroll
            for (int q = 0; q < 4; q++) {
                int row = g * 4 + q;
                int cl  = w * 32 + cf * 16 + li;
                pB[row * 128 + (cl ^ (row * 8))] = f2bf(pm[cf][q]);
            }

        // T14: issue all PV B-operand loads BEFORE the barrier; partial-wait barrier
        // (drain LDS writes only) keeps them in flight across it.
        const unsigned short* hpb = hpbase + (size_t)ct * 4 * FOUT * 32;
        short8 hbv[4][2];
#pragma unroll
        for (int kc = 0; kc < 4; kc++) {
            hbv[kc][0] = *reinterpret_cast<const short8*>(
                &hpb[((size_t)kc * FOUT + w * 32 + li) * 32 + g * 8]);
            hbv[kc][1] = *reinterpret_cast<const short8*>(
                &hpb[((size_t)kc * FOUT + w * 32 + 16 + li) * 32 + g * 8]);
        }
        asm volatile("s_waitcnt lgkmcnt(0)\n\ts_barrier" ::: "memory");

#pragma unroll
        for (int kc = 0; kc < 4; kc++) {
            int k = kc * 32 + g * 8;
            short8 pa = *reinterpret_cast<const short8*>(&pB[li * 128 + (k ^ (li * 8))]);
            __builtin_amdgcn_s_setprio(1);
            oacc[0] = MFMA(pa, hbv[kc][0], oacc[0]);
            oacc[1] = MFMA(pa, hbv[kc][1], oacc[1]);
            __builtin_amdgcn_s_setprio(0);
        }
        if (FIRST) {
#pragma unroll
            for (int i = 0; i < 8; i++) mcur[i] = mnext[i];
        }
    }
}

// ---------------- Kernel 2: MFMA scores (reg-cached, pipelined) -> softmax -> attn + PV ----------------
// grid: BB*(NN/RT2) = 1024 blocks, 256 threads (4 waves). VGPR cap 256 (2 blocks/CU).
__global__ __launch_bounds__(256, 2) void gat_k2(
    const float* __restrict__ mask,   // [B,1,N,N]
    const float* __restrict__ bias,   // [FOUT]
    const unsigned short* __restrict__ asHg,
    const unsigned short* __restrict__ asLg,
    const unsigned short* __restrict__ adHg,
    const unsigned short* __restrict__ adLg,
    const unsigned short* __restrict__ hpPg,  // [B*H][N/32][FOUT][32]
    const float* __restrict__ hpsum,  // [B,N,FOUT]
    float* __restrict__ out,          // [B,N,FOUT]
    float* __restrict__ attn)         // [B,H,N,N]
{
    __shared__ __align__(16) unsigned char smem[8192 + RT2 * MLDS * 2 + 512];
    unsigned short* pBs0  = reinterpret_cast<unsigned short*>(smem);            // 4 KB
    unsigned short* pBs1  = reinterpret_cast<unsigned short*>(smem + 4096);     // 4 KB
    float*          outL  = reinterpret_cast<float*>(smem);                     // 8 KB (epilogue)
    unsigned short* maskL = reinterpret_cast<unsigned short*>(smem + 8192);     // 33 KB
    float2*         red   = reinterpret_cast<float2*>(smem + 8192 + RT2 * MLDS * 2);

    const int t  = threadIdx.x;
    const int l  = t & 63;
    const int w  = t >> 6;
    const int li = l & 15;
    const int g  = l >> 4;

    // XCD-aware bijective swizzle (1024 % 8 == 0)
    const int lb = (blockIdx.x & 7) * 128 + (blockIdx.x >> 3);
    const int b  = lb >> 6;
    const int n0 = (lb & 63) * RT2;

    f32x4 oacc[2];
    oacc[0] = f32x4{0.f, 0.f, 0.f, 0.f};
    oacc[1] = f32x4{0.f, 0.f, 0.f, 0.f};

    for (int hh = 0; hh < HH; hh++) {
        const size_t bh = (size_t)b * HH + hh;

        // A fragments (read-once per block -> NT loads)
        short8 aH[2], aL[2];
#pragma unroll
        for (int ks = 0; ks < 2; ks++) {
            size_t src = (bh * NN + n0 + li) * DD + ks * 32 + g * 8;
            aH[ks] = __builtin_nontemporal_load(reinterpret_cast<const short8*>(&asHg[src]));
            aL[ks] = __builtin_nontemporal_load(reinterpret_cast<const short8*>(&asLg[src]));
        }

        const unsigned short* adHb = adHg + bh * NN * DD;
        const unsigned short* adLb = adLg + bh * NN * DD;

        // ================= pass A: scores -> register cache, 2-deep load pipeline =================
        float sc[8][2][4];
        short8 bHc[2][2], bLc[2][2];   // current tile fragments [cf][ks]
#pragma unroll
        for (int cf = 0; cf < 2; cf++)
#pragma unroll
            for (int ks = 0; ks < 2; ks++) {
                size_t off = (size_t)(w * 32 + cf * 16 + li) * DD + ks * 32 + g * 8;
                bHc[cf][ks] = *reinterpret_cast<const short8*>(&adHb[off]);
                bLc[cf][ks] = *reinterpret_cast<const short8*>(&adLb[off]);
            }
#pragma unroll
        for (int ct = 0; ct < 8; ct++) {
            short8 bHn[2][2], bLn[2][2];
            if (ct < 7) {
#pragma unroll
                for (int cf = 0; cf < 2; cf++)
#pragma unroll
                    for (int ks = 0; ks < 2; ks++) {
                        size_t off = (size_t)((ct + 1) * CT + w * 32 + cf * 16 + li) * DD + ks * 32 + g * 8;
                        bHn[cf][ks] = *reinterpret_cast<const short8*>(&adHb[off]);
                        bLn[cf][ks] = *reinterpret_cast<const short8*>(&adLb[off]);
                    }
            }
#pragma unroll
            for (int cf = 0; cf < 2; cf++) {
                f32x4 s = f32x4{0.f, 0.f, 0.f, 0.f};
                __builtin_amdgcn_s_setprio(1);
#pragma unroll
                for (int ks = 0; ks < 2; ks++) {
                    s = MFMA(aH[ks], bHc[cf][ks], s);
                    s = MFMA(aH[ks], bLc[cf][ks], s);
                    s = MFMA(aL[ks], bHc[cf][ks], s);
                }
                __builtin_amdgcn_s_setprio(0);
#pragma unroll
                for (int q = 0; q < 4; q++) {
                    float v = s[q];
                    sc[ct][cf][q] = v > 0.f ? v : NEG * v;
                }
            }
            if (ct < 7) {
#pragma unroll
                for (int cf = 0; cf < 2; cf++)
#pragma unroll
                    for (int ks = 0; ks < 2; ks++) {
                        bHc[cf][ks] = bHn[cf][ks];
                        bLc[cf][ks] = bLn[cf][ks];
                    }
            }
        }

        // ================= softmax stats from cache =================
        float mreg[4], lreg[4];
#pragma unroll
        for (int q = 0; q < 4; q++) {
            float m = -3.0e38f;
#pragma unroll
            for (int ct = 0; ct < 8; ct++)
                m = fmaxf(m, fmaxf(sc[ct][0][q], sc[ct][1][q]));
            float lv = 0.f;
#pragma unroll
            for (int ct = 0; ct < 8; ct++)
                lv += __expf(sc[ct][0][q] - m) + __expf(sc[ct][1][q] - m);
            mreg[q] = m; lreg[q] = lv;
        }
        // butterfly over the 16 li lanes (cols), then cross-wave via LDS
#pragma unroll
        for (int q = 0; q < 4; q++) {
            float m = mreg[q], lv = lreg[q];
#pragma unroll
            for (int msk = 1; msk < 16; msk <<= 1) {
                float om = __shfl_xor(m, msk);
                float ol = __shfl_xor(lv, msk);
                float nm = fmaxf(m, om);
                lv = lv * __expf(m - nm) + ol * __expf(om - nm);
                m = nm;
            }
            mreg[q] = m; lreg[q] = lv;
        }
        __syncthreads();  // red free (prev head's readers done)
        if (li == 0) {
#pragma unroll
            for (int q = 0; q < 4; q++)
                red[w * 16 + g * 4 + q] = make_float2(mreg[q], lreg[q]);
        }
        __syncthreads();
        float mf[4], linv[4];
#pragma unroll
        for (int q = 0; q < 4; q++) {
            int row = g * 4 + q;
            float2 r0 = red[row], r1 = red[16 + row], r2 = red[32 + row], r3 = red[48 + row];
            float m = fmaxf(fmaxf(r0.x, r1.x), fmaxf(r2.x, r3.x));
            float lv = r0.y * __expf(r0.x - m) + r1.y * __expf(r1.x - m)
                     + r2.y * __expf(r2.x - m) + r3.y * __expf(r3.x - m);
            mf[q] = m;
            linv[q] = 1.0f / lv;
        }

        // ================= pass B =================
        if (hh == 0)
            pass_b<true >(b, n0, w, li, g, bh, sc, mf, linv, mask, attn, hpPg, pBs0, pBs1, maskL, oacc);
        else
            pass_b<false>(b, n0, w, li, g, bh, sc, mf, linv, mask, attn, hpPg, pBs0, pBs1, maskL, oacc);
    }

    // epilogue: stage oacc -> LDS (f32 16x128), then coalesced out write
    __syncthreads();
#pragma unroll
    for (int of = 0; of < 2; of++)
#pragma unroll
        for (int q = 0; q < 4; q++) {
            int row = g * 4 + q;
            int col = w * 32 + of * 16 + li;
            outL[row * 128 + col] = oacc[of][q];
        }
    __syncthreads();
    {
        int row = t >> 4, cb = (t & 15) * 8;
        size_t obase = ((size_t)b * NN + n0 + row) * FOUT + cb;
#pragma unroll
        for (int k4 = 0; k4 < 2; k4++) {
            float4 v  = *reinterpret_cast<float4*>(&outL[row * 128 + cb + k4 * 4]);
            float4 bs = *reinterpret_cast<const float4*>(&bias[cb + k4 * 4]);
            float4 hs = *reinterpret_cast<const float4*>(&hpsum[obase + k4 * 4]);
            v.x += bs.x + hs.x; v.y += bs.y + hs.y; v.z += bs.z + hs.z; v.w += bs.w + hs.w;
            *reinterpret_cast<float4*>(&out[obase + k4 * 4]) = v;
        }
    }
}

extern "C" void kernel_launch(void* const* d_in, const int* in_sizes, int n_in,
                              void* d_out, int out_size, void* d_ws, size_t ws_size,
                              hipStream_t stream) {
    const float* h      = (const float*)d_in[0];
    const float* mask   = (const float*)d_in[1];
    const float* w      = (const float*)d_in[2];
    const float* a_src  = (const float*)d_in[3];
    const float* a_dst  = (const float*)d_in[4];
    const float* bias   = (const float*)d_in[5];

    float* out  = (float*)d_out;                          // [B,N,FOUT]
    float* attn = out + (size_t)BB * NN * FOUT;           // [B,H,N,N]

    // workspace layout (56 MB total)
    const size_t NASD = (size_t)BB * HH * NN * DD;        // 4M elems
    unsigned short* asHg = (unsigned short*)d_ws;
    unsigned short* asLg = asHg + NASD;
    unsigned short* adHg = asLg + NASD;
    unsigned short* adLg = adHg + NASD;
    unsigned short* hpPg = adLg + NASD;                   // B*H*FOUT*N = 8M elems
    float* hpsum = (float*)(hpPg + (size_t)BB * HH * FOUT * NN);

    dim3 block(256);
    gat_k1<<<dim3(BB * (NN / RT)),  block, 0, stream>>>(h, w, a_src, a_dst, asHg, asLg, adHg, adLg, hpPg, hpsum);
    gat_k2<<<dim3(BB * (NN / RT2)), block, 0, stream>>>(mask, bias, asHg, asLg, adHg, adLg, hpPg, hpsum, out, attn);
}